// Round 12
// baseline (528.372 us; speedup 1.0000x reference)
//
#include <hip/hip_runtime.h>
#include <hip/hip_fp16.h>
#include <math.h>

#define NN 50000
#define EE 800000
#define GG 64
#define PAD 48                   // padded CSR bucket (Poisson(16) max-deg << 48)
#define NFB ((EE + 255) / 256)   // fill blocks
#define NT  (NN / 16)            // 3125 16-node tiles

typedef _Float16 f16x8 __attribute__((ext_vector_type(8)));
typedef float f32x4 __attribute__((ext_vector_type(4)));

__device__ __forceinline__ float lrelu(float x) { return x > 0.f ? x : 0.2f * x; }

// ------- CSR fill (1 atomic/edge, padded buckets) + weight prep (grid split) -------
__global__ void k_fill(const int* __restrict__ ei, int* __restrict__ cnt,
                       int* __restrict__ csr,
                       const float* __restrict__ W1, const float* __restrict__ W2,
                       const float* __restrict__ W3, const float* __restrict__ aw1,
                       const float* __restrict__ rw1, const float* __restrict__ cw1,
                       _Float16* __restrict__ wt1, _Float16* __restrict__ wt2,
                       _Float16* __restrict__ wt3, _Float16* __restrict__ wcat) {
  if (blockIdx.x < NFB) {
    const int e = blockIdx.x * 256 + threadIdx.x;
    if (e >= EE) return;
    const int src = ei[e], dst = ei[EE + e];
    const int slot = atomicAdd(&cnt[dst], 1);
    if (slot < PAD) csr[dst * PAD + slot] = src;
    return;
  }
  const int t = (blockIdx.x - NFB) * 256 + threadIdx.x;
  if (t < 32768) {
    const int c = t >> 7, k = t & 127;
    wt1[t] = (_Float16)W1[k * 256 + c];
  } else if (t < 49152) {
    const int u = t - 32768, c = u >> 6, k = u & 63;
    wt2[u] = (_Float16)W2[k * 256 + c];
  } else if (t < 65536) {
    const int u = t - 49152, c = u >> 6, k = u & 63;
    wt3[u] = (_Float16)W3[k * 256 + c];
  } else if (t < 71680) {
    const int u = t - 65536, c = u >> 6, k = u & 63;
    float v = (c < 32) ? aw1[k * 32 + c] : (c < 64) ? rw1[k * 32 + (c - 32)]
                                                    : cw1[k * 32 + (c - 64)];
    wcat[u] = (_Float16)v;
  }
}

// ---------------- h = x@W via MFMA 16x16x32 f16, al_s/al_d fused (layer 1) -------
template <int K, typename XT>
__global__ __launch_bounds__(256) void k_mm(const XT* __restrict__ xin,
                                            const _Float16* __restrict__ wt,
                                            const float* __restrict__ a_s,
                                            const float* __restrict__ a_d,
                                            __half* __restrict__ h,
                                            float* __restrict__ al) {
  constexpr int KC = K / 32;
  const int lane = threadIdx.x & 63;
  const int wv = threadIdx.x >> 6;
  const int quad = lane >> 4, nn = lane & 15;
  f16x8 bf[KC][4];
  float asf[4], adf[4];
#pragma unroll
  for (int ct = 0; ct < 4; ++ct) {
    const int col = wv * 64 + ct * 16 + nn;
#pragma unroll
    for (int kc = 0; kc < KC; ++kc)
      bf[kc][ct] = *(const f16x8*)&wt[(size_t)col * K + kc * 32 + quad * 8];
    asf[ct] = a_s[col];
    adf[ct] = a_d[col];
  }
  for (int rt = blockIdx.x; rt < NT; rt += gridDim.x) {
    const int row0 = rt * 16;
    const XT* xrow = xin + (size_t)(row0 + nn) * K + quad * 8;
    f16x8 af[KC];
#pragma unroll
    for (int kc = 0; kc < KC; ++kc) {
      if constexpr (sizeof(XT) == 2) {
        af[kc] = *(const f16x8*)(xrow + kc * 32);
      } else {
        const float4 u0 = *(const float4*)(xrow + kc * 32);
        const float4 u1 = *(const float4*)(xrow + kc * 32 + 4);
        af[kc][0] = (_Float16)u0.x; af[kc][1] = (_Float16)u0.y;
        af[kc][2] = (_Float16)u0.z; af[kc][3] = (_Float16)u0.w;
        af[kc][4] = (_Float16)u1.x; af[kc][5] = (_Float16)u1.y;
        af[kc][6] = (_Float16)u1.z; af[kc][7] = (_Float16)u1.w;
      }
    }
    f32x4 accv[4];
#pragma unroll
    for (int ct = 0; ct < 4; ++ct) {
      f32x4 acc = {0.f, 0.f, 0.f, 0.f};
#pragma unroll
      for (int kc = 0; kc < KC; ++kc)
        acc = __builtin_amdgcn_mfma_f32_16x16x32_f16(af[kc], bf[kc][ct], acc, 0, 0, 0);
      accv[ct] = acc;
      const int col = wv * 64 + ct * 16 + nn;
#pragma unroll
      for (int r = 0; r < 4; ++r)
        h[(size_t)(row0 + quad * 4 + r) * 256 + col] = __float2half(acc[r]);
    }
    float sa[4] = {0.f, 0.f, 0.f, 0.f}, sd[4] = {0.f, 0.f, 0.f, 0.f};
#pragma unroll
    for (int ct = 0; ct < 4; ++ct)
#pragma unroll
      for (int r = 0; r < 4; ++r) {
        sa[r] = fmaf(accv[ct][r], asf[ct], sa[r]);
        sd[r] = fmaf(accv[ct][r], adf[ct], sd[r]);
      }
#pragma unroll
    for (int off = 1; off <= 8; off <<= 1)
#pragma unroll
      for (int r = 0; r < 4; ++r) {
        sa[r] += __shfl_xor(sa[r], off, 64);
        sd[r] += __shfl_xor(sd[r], off, 64);
      }
    if (nn == 0) {
#pragma unroll
      for (int r = 0; r < 4; ++r) {
        al[(size_t)(row0 + quad * 4 + r) * 8 + wv] = sa[r];
        al[(size_t)(row0 + quad * 4 + r) * 8 + 4 + wv] = sd[r];
      }
    }
  }
}

// ------- agg of 16 nodes (2 passes of 8) into LDS fp16 tile xt[16][72] -------
// RELU: apply relu before storing tile. WRITE_EMB: also store fp32 rows to embout.
template <bool RELU, bool WRITE_EMB>
__device__ __forceinline__ void agg16(const __half* __restrict__ h,
                                      const float* __restrict__ al,
                                      const int* __restrict__ cnt,
                                      const int* __restrict__ csr,
                                      const float* __restrict__ bias,
                                      float* __restrict__ embout,
                                      _Float16* __restrict__ xt) {
  const int tid = threadIdx.x;
  const int l32 = tid & 31;
  const int head = l32 >> 3;
  const int row0 = blockIdx.x * 16;
  const __half* hbase = h + (size_t)l32 * 8;
  union U { int4 v; __half2 h2[4]; };
  for (int q = 0; q < 2; ++q) {
    const int n = row0 + q * 8 + (tid >> 5);
    const int start = n * PAD;
    const int deg = min(cnt[n], PAD);
    const int end = start + deg;
    const float ald_my = al[n * 8 + 4 + head];
    float acc[8] = {};
    float denom = 0.f;
    {  // analytic self-loop
      U cv;
      cv.v = *(const int4*)(hbase + (size_t)n * 256);
      const float p = __expf(lrelu(al[n * 8 + head] + ald_my));
      denom += p;
      float2 f;
#pragma unroll
      for (int j = 0; j < 4; ++j) {
        f = __half22float2(cv.h2[j]);
        acc[2 * j] = fmaf(p, f.x, acc[2 * j]);
        acc[2 * j + 1] = fmaf(p, f.y, acc[2 * j + 1]);
      }
    }
    int i = start;
    const int e8 = start + (deg & ~7);
    for (; i < e8; i += 8) {
      int s[8];
#pragma unroll
      for (int u = 0; u < 8; ++u) s[u] = csr[i + u];
      U c[8];
#pragma unroll
      for (int u = 0; u < 8; ++u) c[u].v = *(const int4*)(hbase + (size_t)s[u] * 256);
      float p[8];
#pragma unroll
      for (int u = 0; u < 8; ++u) p[u] = __expf(lrelu(al[s[u] * 8 + head] + ald_my));
#pragma unroll
      for (int u = 0; u < 8; ++u) denom += p[u];
#pragma unroll
      for (int u = 0; u < 8; ++u) {
        float2 f;
#pragma unroll
        for (int j = 0; j < 4; ++j) {
          f = __half22float2(c[u].h2[j]);
          acc[2 * j] = fmaf(p[u], f.x, acc[2 * j]);
          acc[2 * j + 1] = fmaf(p[u], f.y, acc[2 * j + 1]);
        }
      }
    }
    const int e4 = i + ((end - i) & ~3);
    for (; i < e4; i += 4) {
      int s[4];
#pragma unroll
      for (int u = 0; u < 4; ++u) s[u] = csr[i + u];
      U c[4];
#pragma unroll
      for (int u = 0; u < 4; ++u) c[u].v = *(const int4*)(hbase + (size_t)s[u] * 256);
      float p[4];
#pragma unroll
      for (int u = 0; u < 4; ++u) p[u] = __expf(lrelu(al[s[u] * 8 + head] + ald_my));
#pragma unroll
      for (int u = 0; u < 4; ++u) denom += p[u];
#pragma unroll
      for (int u = 0; u < 4; ++u) {
        float2 f;
#pragma unroll
        for (int j = 0; j < 4; ++j) {
          f = __half22float2(c[u].h2[j]);
          acc[2 * j] = fmaf(p[u], f.x, acc[2 * j]);
          acc[2 * j + 1] = fmaf(p[u], f.y, acc[2 * j + 1]);
        }
      }
    }
    for (; i < end; ++i) {
      const int s = csr[i];
      U cv;
      cv.v = *(const int4*)(hbase + (size_t)s * 256);
      const float p = __expf(lrelu(al[s * 8 + head] + ald_my));
      denom += p;
      float2 f;
#pragma unroll
      for (int j = 0; j < 4; ++j) {
        f = __half22float2(cv.h2[j]);
        acc[2 * j] = fmaf(p, f.x, acc[2 * j]);
        acc[2 * j + 1] = fmaf(p, f.y, acc[2 * j + 1]);
      }
    }
    const float inv = 0.25f / denom;  // alpha normalize + head mean
#pragma unroll
    for (int j = 0; j < 8; ++j) acc[j] *= inv;
#pragma unroll
    for (int j = 0; j < 8; ++j) acc[j] += __shfl_xor(acc[j], 8, 64);
#pragma unroll
    for (int j = 0; j < 8; ++j) acc[j] += __shfl_xor(acc[j], 16, 64);
    if (l32 < 8) {
      const float4 b0 = *(const float4*)&bias[l32 * 8];
      const float4 b1 = *(const float4*)&bias[l32 * 8 + 4];
      float o[8];
      o[0] = acc[0] + b0.x; o[1] = acc[1] + b0.y; o[2] = acc[2] + b0.z; o[3] = acc[3] + b0.w;
      o[4] = acc[4] + b1.x; o[5] = acc[5] + b1.y; o[6] = acc[6] + b1.z; o[7] = acc[7] + b1.w;
      if (RELU) {
#pragma unroll
        for (int j = 0; j < 8; ++j) o[j] = fmaxf(o[j], 0.f);
      }
      const int node = q * 8 + (tid >> 5) - (tid >> 5 >= 8 ? 8 : 0);  // placeholder
      (void)node;
      const int nd = q * 8 + ((tid >> 5) & 7);
      f16x8 v;
#pragma unroll
      for (int j = 0; j < 8; ++j) v[j] = (_Float16)o[j];
      *(f16x8*)(xt + nd * 72 + l32 * 8) = v;
      if (WRITE_EMB) {
        float4 v0 = {o[0], o[1], o[2], o[3]}, v1 = {o[4], o[5], o[6], o[7]};
        *(float4*)&embout[(size_t)(row0 + nd) * 64 + l32 * 8] = v0;
        *(float4*)&embout[(size_t)(row0 + nd) * 64 + l32 * 8 + 4] = v1;
      }
    }
  }
}

// ------- fused agg_i + linear_{i+1}: h,al -> h2,al2 (xt tile never hits global) -----
__global__ __launch_bounds__(256) void k_aggmm(const __half* __restrict__ h,
                                               const float* __restrict__ al,
                                               const int* __restrict__ cnt,
                                               const int* __restrict__ csr,
                                               const float* __restrict__ bias,
                                               const _Float16* __restrict__ wt,
                                               const float* __restrict__ a_s,
                                               const float* __restrict__ a_d,
                                               __half* __restrict__ h2,
                                               float* __restrict__ al2) {
  __shared__ _Float16 xt[16 * 72];
  const int lane = threadIdx.x & 63;
  const int wv = threadIdx.x >> 6;
  const int quad = lane >> 4, nn = lane & 15;
  f16x8 bf[2][4];
  float asf[4], adf[4];
#pragma unroll
  for (int ct = 0; ct < 4; ++ct) {
    const int col = wv * 64 + ct * 16 + nn;
#pragma unroll
    for (int kc = 0; kc < 2; ++kc)
      bf[kc][ct] = *(const f16x8*)&wt[(size_t)col * 64 + kc * 32 + quad * 8];
    asf[ct] = a_s[col];
    adf[ct] = a_d[col];
  }
  agg16<true, false>(h, al, cnt, csr, bias, nullptr, xt);
  __syncthreads();
  const int row0 = blockIdx.x * 16;
  f16x8 af[2];
#pragma unroll
  for (int kc = 0; kc < 2; ++kc)
    af[kc] = *(const f16x8*)(xt + nn * 72 + kc * 32 + quad * 8);
  f32x4 accv[4];
#pragma unroll
  for (int ct = 0; ct < 4; ++ct) {
    f32x4 acc = {0.f, 0.f, 0.f, 0.f};
#pragma unroll
    for (int kc = 0; kc < 2; ++kc)
      acc = __builtin_amdgcn_mfma_f32_16x16x32_f16(af[kc], bf[kc][ct], acc, 0, 0, 0);
    accv[ct] = acc;
    const int col = wv * 64 + ct * 16 + nn;
#pragma unroll
    for (int r = 0; r < 4; ++r)
      h2[(size_t)(row0 + quad * 4 + r) * 256 + col] = __float2half(acc[r]);
  }
  float sa[4] = {0.f, 0.f, 0.f, 0.f}, sd[4] = {0.f, 0.f, 0.f, 0.f};
#pragma unroll
  for (int ct = 0; ct < 4; ++ct)
#pragma unroll
    for (int r = 0; r < 4; ++r) {
      sa[r] = fmaf(accv[ct][r], asf[ct], sa[r]);
      sd[r] = fmaf(accv[ct][r], adf[ct], sd[r]);
    }
#pragma unroll
  for (int off = 1; off <= 8; off <<= 1)
#pragma unroll
    for (int r = 0; r < 4; ++r) {
      sa[r] += __shfl_xor(sa[r], off, 64);
      sd[r] += __shfl_xor(sd[r], off, 64);
    }
  if (nn == 0) {
#pragma unroll
    for (int r = 0; r < 4; ++r) {
      al2[(size_t)(row0 + quad * 4 + r) * 8 + wv] = sa[r];
      al2[(size_t)(row0 + quad * 4 + r) * 8 + 4 + wv] = sd[r];
    }
  }
}

// ------- fused agg3 + node-MLP heads: h,al -> emb + anomaly/risk/resource -------
__global__ __launch_bounds__(256) void k_aggheads(const __half* __restrict__ h,
                                                  const float* __restrict__ al,
                                                  const int* __restrict__ cnt,
                                                  const int* __restrict__ csr,
                                                  const float* __restrict__ bias,
                                                  const _Float16* __restrict__ wcat,
                                                  const float* __restrict__ aw2,
                                                  const float* __restrict__ ab2,
                                                  const float* __restrict__ rw2,
                                                  const float* __restrict__ rb2,
                                                  const float* __restrict__ cw2,
                                                  const float* __restrict__ cb2,
                                                  float* __restrict__ emb,
                                                  float* __restrict__ anomaly,
                                                  float* __restrict__ risk,
                                                  float* __restrict__ resource) {
  __shared__ _Float16 xt[16 * 72];
  __shared__ float hb[16][101];
  const int lane = threadIdx.x & 63;
  const int wv = threadIdx.x >> 6;
  const int quad = lane >> 4, nn = lane & 15;
  // wave wv handles ct = wv, plus ct = 4+wv for wv<2 (6 col-tiles of wcat[96][64])
  const int nct = (wv < 2) ? 2 : 1;
  f16x8 bf[2][2];
#pragma unroll
  for (int m = 0; m < 2; ++m) {
    if (m < nct) {
      const int ct = (m == 0) ? wv : (4 + wv);
      const int col = ct * 16 + nn;
#pragma unroll
      for (int kc = 0; kc < 2; ++kc)
        bf[kc][m] = *(const f16x8*)&wcat[(size_t)col * 64 + kc * 32 + quad * 8];
    }
  }
  agg16<false, true>(h, al, cnt, csr, bias, emb, xt);
  __syncthreads();
  f16x8 af[2];
#pragma unroll
  for (int kc = 0; kc < 2; ++kc)
    af[kc] = *(const f16x8*)(xt + nn * 72 + kc * 32 + quad * 8);
#pragma unroll
  for (int m = 0; m < 2; ++m) {
    if (m < nct) {
      const int ct = (m == 0) ? wv : (4 + wv);
      f32x4 acc = {0.f, 0.f, 0.f, 0.f};
#pragma unroll
      for (int kc = 0; kc < 2; ++kc)
        acc = __builtin_amdgcn_mfma_f32_16x16x32_f16(af[kc], bf[kc][m], acc, 0, 0, 0);
      const int col = ct * 16 + nn;
#pragma unroll
      for (int r = 0; r < 4; ++r)
        hb[quad * 4 + r][col] = fmaxf(acc[r], 0.f);
    }
  }
  __syncthreads();
  if (wv == 0) {
    const int node = lane >> 2, task = lane & 3;
    const float* hrow = hb[node];
    const int n = blockIdx.x * 16 + node;
    if (task == 0) {
      float s = ab2[0];
#pragma unroll
      for (int k = 0; k < 32; ++k) s = fmaf(hrow[k], aw2[k], s);
      anomaly[n] = 1.f / (1.f + __expf(-s));
    } else if (task == 1) {
      float s = rb2[0];
#pragma unroll
      for (int k = 0; k < 32; ++k) s = fmaf(hrow[32 + k], rw2[k], s);
      risk[n] = 1.f / (1.f + __expf(-s));
    } else if (task == 2) {
      float s0 = cb2[0], s1 = cb2[1], s2 = cb2[2];
#pragma unroll
      for (int k = 0; k < 32; ++k) {
        const float v = hrow[64 + k];
        s0 = fmaf(v, cw2[k * 5 + 0], s0);
        s1 = fmaf(v, cw2[k * 5 + 1], s1);
        s2 = fmaf(v, cw2[k * 5 + 2], s2);
      }
      resource[n * 5 + 0] = s0; resource[n * 5 + 1] = s1; resource[n * 5 + 2] = s2;
    } else {
      float s3 = cb2[3], s4 = cb2[4];
#pragma unroll
      for (int k = 0; k < 32; ++k) {
        const float v = hrow[64 + k];
        s3 = fmaf(v, cw2[k * 5 + 3], s3);
        s4 = fmaf(v, cw2[k * 5 + 4], s4);
      }
      resource[n * 5 + 3] = s3; resource[n * 5 + 4] = s4;
    }
  }
}

// ---------------- pooling + graph MLP (1 block per graph; batch is SORTED) -------
__global__ void k_pool(const float* __restrict__ emb, const int* __restrict__ batch,
                       const float* __restrict__ gw1, const float* __restrict__ gb1,
                       const float* __restrict__ gw2, const float* __restrict__ gb2,
                       float* __restrict__ logits) {
  const int g = blockIdx.x;
  const int tid = threadIdx.x;
  const int c = tid & 63, w = tid >> 6;
  int lo = 0, hi = NN;
  while (lo < hi) { int mid = (lo + hi) >> 1; if (batch[mid] < g) lo = mid + 1; else hi = mid; }
  const int start = lo;
  hi = NN;
  while (lo < hi) { int mid = (lo + hi) >> 1; if (batch[mid] < g + 1) lo = mid + 1; else hi = mid; }
  const int end = lo;
  float s = 0.f;
  for (int n = start + w; n < end; n += 4) s += emb[n * 64 + c];
  __shared__ float sm[4][64];
  __shared__ float prow[64];
  sm[w][c] = s;
  __syncthreads();
  if (tid < 64) {
    float v = sm[0][tid] + sm[1][tid] + sm[2][tid] + sm[3][tid];
    prow[tid] = v * (1.f / fmaxf((float)(end - start), 1.f));
  }
  __syncthreads();
  if (tid < 32) {
    float hG = gb1[tid];
    for (int cc = 0; cc < 64; ++cc) hG = fmaf(prow[cc], gw1[cc * 32 + tid], hG);
    hG = fmaxf(hG, 0.f);
    float p[4];
#pragma unroll
    for (int j = 0; j < 4; ++j) p[j] = hG * gw2[tid * 4 + j];
#pragma unroll
    for (int off = 1; off <= 16; off <<= 1) {
#pragma unroll
      for (int j = 0; j < 4; ++j) p[j] += __shfl_xor(p[j], off, 64);
    }
    if (tid == 0) {
#pragma unroll
      for (int j = 0; j < 4; ++j) logits[g * 4 + j] = p[j] + gb2[j];
    }
  }
}

extern "C" void kernel_launch(void* const* d_in, const int* in_sizes, int n_in,
                              void* d_out, int out_size, void* d_ws, size_t ws_size,
                              hipStream_t stream) {
  const float* x = (const float*)d_in[0];
  const int* ei = (const int*)d_in[1];
  const int* batch = (const int*)d_in[2];
  const float* W1 = (const float*)d_in[3];
  const float* as1 = (const float*)d_in[4];
  const float* ad1 = (const float*)d_in[5];
  const float* b1 = (const float*)d_in[6];
  const float* W2 = (const float*)d_in[7];
  const float* as2 = (const float*)d_in[8];
  const float* ad2 = (const float*)d_in[9];
  const float* b2 = (const float*)d_in[10];
  const float* W3 = (const float*)d_in[11];
  const float* as3 = (const float*)d_in[12];
  const float* ad3 = (const float*)d_in[13];
  const float* b3 = (const float*)d_in[14];
  const float* aw1 = (const float*)d_in[15];
  const float* ab1 = (const float*)d_in[16];
  const float* aw2 = (const float*)d_in[17];
  const float* ab2 = (const float*)d_in[18];
  const float* rw1 = (const float*)d_in[19];
  const float* rb1 = (const float*)d_in[20];
  const float* rw2 = (const float*)d_in[21];
  const float* rb2 = (const float*)d_in[22];
  const float* cw1 = (const float*)d_in[23];
  const float* cb1 = (const float*)d_in[24];
  const float* cw2 = (const float*)d_in[25];
  const float* cb2 = (const float*)d_in[26];
  const float* gw1 = (const float*)d_in[27];
  const float* gb1 = (const float*)d_in[28];
  const float* gw2 = (const float*)d_in[29];
  const float* gb2 = (const float*)d_in[30];

  float* out = (float*)d_out;
  float* emb = out;                       // [N,64]
  float* anomaly = out + NN * 64;         // [N]
  float* risk = anomaly + NN;             // [N]
  float* resource = risk + NN;            // [N,5]
  float* logits = resource + NN * 5;      // [G,4]

  char* ws = (char*)d_ws;
  int* cnt = (int*)ws;            ws += (size_t)NN * 4;   // memset target
  int* csr = (int*)ws;            ws += (size_t)NN * PAD * 4;
  __half* hA = (__half*)ws;       ws += (size_t)NN * 256 * 2;
  float* alA = (float*)ws;        ws += (size_t)NN * 8 * 4;
  __half* hB = (__half*)ws;       ws += (size_t)NN * 256 * 2;
  float* alB = (float*)ws;        ws += (size_t)NN * 8 * 4;
  _Float16* wt1 = (_Float16*)ws;  ws += (size_t)32768 * 2;
  _Float16* wt2 = (_Float16*)ws;  ws += (size_t)16384 * 2;
  _Float16* wt3 = (_Float16*)ws;  ws += (size_t)16384 * 2;
  _Float16* wcat = (_Float16*)ws; ws += (size_t)6144 * 2;

  hipMemsetAsync(cnt, 0, (size_t)NN * 4, stream);
  k_fill<<<NFB + 280, 256, 0, stream>>>(ei, cnt, csr, W1, W2, W3, aw1, rw1, cw1,
                                        wt1, wt2, wt3, wcat);

  // layer 1 linear (fp32 x, in-register cvt)
  k_mm<128, float><<<512, 256, 0, stream>>>(x, wt1, as1, ad1, hA, alA);
  // agg1 + linear2 fused
  k_aggmm<<<NT, 256, 0, stream>>>(hA, alA, cnt, csr, b1, wt2, as2, ad2, hB, alB);
  // agg2 + linear3 fused
  k_aggmm<<<NT, 256, 0, stream>>>(hB, alB, cnt, csr, b2, wt3, as3, ad3, hA, alA);
  // agg3 + node-MLP heads fused
  k_aggheads<<<NT, 256, 0, stream>>>(hA, alA, cnt, csr, b3, wcat, aw2, ab2, rw2, rb2,
                                     cw2, cb2, emb, anomaly, risk, resource);
  k_pool<<<GG, 256, 0, stream>>>(emb, batch, gw1, gb1, gw2, gb2, logits);
}

// Round 13
// 517.740 us; speedup vs baseline: 1.0205x; 1.0205x over previous
//
#include <hip/hip_runtime.h>
#include <hip/hip_fp16.h>
#include <math.h>

#define NN 50000
#define EE 800000
#define GG 64
#define PAD 48                   // padded CSR bucket (Poisson(16) max-deg << 48)
#define NFB ((EE + 255) / 256)   // fill blocks
#define NT  (NN / 16)            // 3125 16-node tiles

typedef _Float16 f16x8 __attribute__((ext_vector_type(8)));
typedef float f32x4 __attribute__((ext_vector_type(4)));

__device__ __forceinline__ float lrelu(float x) { return x > 0.f ? x : 0.2f * x; }

// ------- CSR fill (1 atomic/edge, padded buckets) + weight prep (grid split) -------
__global__ void k_fill(const int* __restrict__ ei, int* __restrict__ cnt,
                       int* __restrict__ csr,
                       const float* __restrict__ W1, const float* __restrict__ W2,
                       const float* __restrict__ W3, const float* __restrict__ aw1,
                       const float* __restrict__ rw1, const float* __restrict__ cw1,
                       _Float16* __restrict__ wt1, _Float16* __restrict__ wt2,
                       _Float16* __restrict__ wt3, _Float16* __restrict__ wcat) {
  if (blockIdx.x < NFB) {
    const int e = blockIdx.x * 256 + threadIdx.x;
    if (e >= EE) return;
    const int src = ei[e], dst = ei[EE + e];
    const int slot = atomicAdd(&cnt[dst], 1);
    if (slot < PAD) csr[dst * PAD + slot] = src;
    return;
  }
  const int t = (blockIdx.x - NFB) * 256 + threadIdx.x;
  if (t < 32768) {
    const int c = t >> 7, k = t & 127;
    wt1[t] = (_Float16)W1[k * 256 + c];
  } else if (t < 49152) {
    const int u = t - 32768, c = u >> 6, k = u & 63;
    wt2[u] = (_Float16)W2[k * 256 + c];
  } else if (t < 65536) {
    const int u = t - 49152, c = u >> 6, k = u & 63;
    wt3[u] = (_Float16)W3[k * 256 + c];
  } else if (t < 71680) {
    const int u = t - 65536, c = u >> 6, k = u & 63;
    float v = (c < 32) ? aw1[k * 32 + c] : (c < 64) ? rw1[k * 32 + (c - 32)]
                                                    : cw1[k * 32 + (c - 64)];
    wcat[u] = (_Float16)v;
  }
}

// ---------------- h = x@W via MFMA 16x16x32 f16, al_s/al_d fused (layer 1) -------
template <int K, typename XT>
__global__ __launch_bounds__(256) void k_mm(const XT* __restrict__ xin,
                                            const _Float16* __restrict__ wt,
                                            const float* __restrict__ a_s,
                                            const float* __restrict__ a_d,
                                            __half* __restrict__ h,
                                            float* __restrict__ al) {
  constexpr int KC = K / 32;
  const int lane = threadIdx.x & 63;
  const int wv = threadIdx.x >> 6;
  const int quad = lane >> 4, nn = lane & 15;
  f16x8 bf[KC][4];
  float asf[4], adf[4];
#pragma unroll
  for (int ct = 0; ct < 4; ++ct) {
    const int col = wv * 64 + ct * 16 + nn;
#pragma unroll
    for (int kc = 0; kc < KC; ++kc)
      bf[kc][ct] = *(const f16x8*)&wt[(size_t)col * K + kc * 32 + quad * 8];
    asf[ct] = a_s[col];
    adf[ct] = a_d[col];
  }
  for (int rt = blockIdx.x; rt < NT; rt += gridDim.x) {
    const int row0 = rt * 16;
    const XT* xrow = xin + (size_t)(row0 + nn) * K + quad * 8;
    f16x8 af[KC];
#pragma unroll
    for (int kc = 0; kc < KC; ++kc) {
      if constexpr (sizeof(XT) == 2) {
        af[kc] = *(const f16x8*)(xrow + kc * 32);
      } else {
        const float4 u0 = *(const float4*)(xrow + kc * 32);
        const float4 u1 = *(const float4*)(xrow + kc * 32 + 4);
        af[kc][0] = (_Float16)u0.x; af[kc][1] = (_Float16)u0.y;
        af[kc][2] = (_Float16)u0.z; af[kc][3] = (_Float16)u0.w;
        af[kc][4] = (_Float16)u1.x; af[kc][5] = (_Float16)u1.y;
        af[kc][6] = (_Float16)u1.z; af[kc][7] = (_Float16)u1.w;
      }
    }
    f32x4 accv[4];
#pragma unroll
    for (int ct = 0; ct < 4; ++ct) {
      f32x4 acc = {0.f, 0.f, 0.f, 0.f};
#pragma unroll
      for (int kc = 0; kc < KC; ++kc)
        acc = __builtin_amdgcn_mfma_f32_16x16x32_f16(af[kc], bf[kc][ct], acc, 0, 0, 0);
      accv[ct] = acc;
      const int col = wv * 64 + ct * 16 + nn;
#pragma unroll
      for (int r = 0; r < 4; ++r)
        h[(size_t)(row0 + quad * 4 + r) * 256 + col] = __float2half(acc[r]);
    }
    float sa[4] = {0.f, 0.f, 0.f, 0.f}, sd[4] = {0.f, 0.f, 0.f, 0.f};
#pragma unroll
    for (int ct = 0; ct < 4; ++ct)
#pragma unroll
      for (int r = 0; r < 4; ++r) {
        sa[r] = fmaf(accv[ct][r], asf[ct], sa[r]);
        sd[r] = fmaf(accv[ct][r], adf[ct], sd[r]);
      }
#pragma unroll
    for (int off = 1; off <= 8; off <<= 1)
#pragma unroll
      for (int r = 0; r < 4; ++r) {
        sa[r] += __shfl_xor(sa[r], off, 64);
        sd[r] += __shfl_xor(sd[r], off, 64);
      }
    if (nn == 0) {
#pragma unroll
      for (int r = 0; r < 4; ++r) {
        al[(size_t)(row0 + quad * 4 + r) * 8 + wv] = sa[r];
        al[(size_t)(row0 + quad * 4 + r) * 8 + 4 + wv] = sd[r];
      }
    }
  }
}

// ------- agg of 16 nodes (2 passes of 8) into LDS fp16 tile xt[16][72] -------
template <bool RELU, bool WRITE_EMB>
__device__ __forceinline__ void agg16(const __half* __restrict__ h,
                                      const float* __restrict__ al,
                                      const int* __restrict__ cnt,
                                      const int* __restrict__ csr,
                                      const float* __restrict__ bias,
                                      float* __restrict__ embout,
                                      _Float16* __restrict__ xt) {
  const int tid = threadIdx.x;
  const int l32 = tid & 31;
  const int head = l32 >> 3;
  const int row0 = blockIdx.x * 16;
  const __half* hbase = h + (size_t)l32 * 8;
  union U { int4 v; __half2 h2[4]; };
  for (int q = 0; q < 2; ++q) {
    const int n = row0 + q * 8 + (tid >> 5);
    const int start = n * PAD;
    const int deg = min(cnt[n], PAD);
    const int end = start + deg;
    const float ald_my = al[n * 8 + 4 + head];
    float acc[8] = {};
    float denom = 0.f;
    {  // analytic self-loop
      U cv;
      cv.v = *(const int4*)(hbase + (size_t)n * 256);
      const float p = __expf(lrelu(al[n * 8 + head] + ald_my));
      denom += p;
      float2 f;
#pragma unroll
      for (int j = 0; j < 4; ++j) {
        f = __half22float2(cv.h2[j]);
        acc[2 * j] = fmaf(p, f.x, acc[2 * j]);
        acc[2 * j + 1] = fmaf(p, f.y, acc[2 * j + 1]);
      }
    }
    int i = start;
    const int e8 = start + (deg & ~7);
    for (; i < e8; i += 8) {
      int s[8];
#pragma unroll
      for (int u = 0; u < 8; ++u) s[u] = csr[i + u];
      U c[8];
#pragma unroll
      for (int u = 0; u < 8; ++u) c[u].v = *(const int4*)(hbase + (size_t)s[u] * 256);
      float p[8];
#pragma unroll
      for (int u = 0; u < 8; ++u) p[u] = __expf(lrelu(al[s[u] * 8 + head] + ald_my));
#pragma unroll
      for (int u = 0; u < 8; ++u) denom += p[u];
#pragma unroll
      for (int u = 0; u < 8; ++u) {
        float2 f;
#pragma unroll
        for (int j = 0; j < 4; ++j) {
          f = __half22float2(c[u].h2[j]);
          acc[2 * j] = fmaf(p[u], f.x, acc[2 * j]);
          acc[2 * j + 1] = fmaf(p[u], f.y, acc[2 * j + 1]);
        }
      }
    }
    const int e4 = i + ((end - i) & ~3);
    for (; i < e4; i += 4) {
      int s[4];
#pragma unroll
      for (int u = 0; u < 4; ++u) s[u] = csr[i + u];
      U c[4];
#pragma unroll
      for (int u = 0; u < 4; ++u) c[u].v = *(const int4*)(hbase + (size_t)s[u] * 256);
      float p[4];
#pragma unroll
      for (int u = 0; u < 4; ++u) p[u] = __expf(lrelu(al[s[u] * 8 + head] + ald_my));
#pragma unroll
      for (int u = 0; u < 4; ++u) denom += p[u];
#pragma unroll
      for (int u = 0; u < 4; ++u) {
        float2 f;
#pragma unroll
        for (int j = 0; j < 4; ++j) {
          f = __half22float2(c[u].h2[j]);
          acc[2 * j] = fmaf(p[u], f.x, acc[2 * j]);
          acc[2 * j + 1] = fmaf(p[u], f.y, acc[2 * j + 1]);
        }
      }
    }
    for (; i < end; ++i) {
      const int s = csr[i];
      U cv;
      cv.v = *(const int4*)(hbase + (size_t)s * 256);
      const float p = __expf(lrelu(al[s * 8 + head] + ald_my));
      denom += p;
      float2 f;
#pragma unroll
      for (int j = 0; j < 4; ++j) {
        f = __half22float2(cv.h2[j]);
        acc[2 * j] = fmaf(p, f.x, acc[2 * j]);
        acc[2 * j + 1] = fmaf(p, f.y, acc[2 * j + 1]);
      }
    }
    const float inv = 0.25f / denom;  // alpha normalize + head mean
#pragma unroll
    for (int j = 0; j < 8; ++j) acc[j] *= inv;
#pragma unroll
    for (int j = 0; j < 8; ++j) acc[j] += __shfl_xor(acc[j], 8, 64);
#pragma unroll
    for (int j = 0; j < 8; ++j) acc[j] += __shfl_xor(acc[j], 16, 64);
    if (l32 < 8) {
      const float4 b0 = *(const float4*)&bias[l32 * 8];
      const float4 b1 = *(const float4*)&bias[l32 * 8 + 4];
      float o[8];
      o[0] = acc[0] + b0.x; o[1] = acc[1] + b0.y; o[2] = acc[2] + b0.z; o[3] = acc[3] + b0.w;
      o[4] = acc[4] + b1.x; o[5] = acc[5] + b1.y; o[6] = acc[6] + b1.z; o[7] = acc[7] + b1.w;
      if (RELU) {
#pragma unroll
        for (int j = 0; j < 8; ++j) o[j] = fmaxf(o[j], 0.f);
      }
      const int nd = q * 8 + ((tid >> 5) & 7);
      f16x8 v;
#pragma unroll
      for (int j = 0; j < 8; ++j) v[j] = (_Float16)o[j];
      *(f16x8*)(xt + nd * 72 + l32 * 8) = v;
      if (WRITE_EMB) {
        float4 v0 = {o[0], o[1], o[2], o[3]}, v1 = {o[4], o[5], o[6], o[7]};
        *(float4*)&embout[(size_t)(row0 + nd) * 64 + l32 * 8] = v0;
        *(float4*)&embout[(size_t)(row0 + nd) * 64 + l32 * 8 + 4] = v1;
      }
    }
  }
}

// ------- fused agg_i + linear_{i+1}: B-frags loaded AFTER agg (VGPR pressure) ------
__global__ __launch_bounds__(256) void k_aggmm(const __half* __restrict__ h,
                                               const float* __restrict__ al,
                                               const int* __restrict__ cnt,
                                               const int* __restrict__ csr,
                                               const float* __restrict__ bias,
                                               const _Float16* __restrict__ wt,
                                               const float* __restrict__ a_s,
                                               const float* __restrict__ a_d,
                                               __half* __restrict__ h2,
                                               float* __restrict__ al2) {
  __shared__ _Float16 xt[16 * 72];
  agg16<true, false>(h, al, cnt, csr, bias, nullptr, xt);
  __syncthreads();   // also fences: wt/a_s/a_d loads below cannot hoist above
  const int lane = threadIdx.x & 63;
  const int wv = threadIdx.x >> 6;
  const int quad = lane >> 4, nn = lane & 15;
  const int row0 = blockIdx.x * 16;
  f16x8 af[2];
#pragma unroll
  for (int kc = 0; kc < 2; ++kc)
    af[kc] = *(const f16x8*)(xt + nn * 72 + kc * 32 + quad * 8);
  f32x4 accv[4];
  float asf[4], adf[4];
#pragma unroll
  for (int ct = 0; ct < 4; ++ct) {
    const int col = wv * 64 + ct * 16 + nn;
    f16x8 b0 = *(const f16x8*)&wt[(size_t)col * 64 + quad * 8];
    f16x8 b1 = *(const f16x8*)&wt[(size_t)col * 64 + 32 + quad * 8];
    asf[ct] = a_s[col];
    adf[ct] = a_d[col];
    f32x4 acc = {0.f, 0.f, 0.f, 0.f};
    acc = __builtin_amdgcn_mfma_f32_16x16x32_f16(af[0], b0, acc, 0, 0, 0);
    acc = __builtin_amdgcn_mfma_f32_16x16x32_f16(af[1], b1, acc, 0, 0, 0);
    accv[ct] = acc;
#pragma unroll
    for (int r = 0; r < 4; ++r)
      h2[(size_t)(row0 + quad * 4 + r) * 256 + col] = __float2half(acc[r]);
  }
  float sa[4] = {0.f, 0.f, 0.f, 0.f}, sd[4] = {0.f, 0.f, 0.f, 0.f};
#pragma unroll
  for (int ct = 0; ct < 4; ++ct)
#pragma unroll
    for (int r = 0; r < 4; ++r) {
      sa[r] = fmaf(accv[ct][r], asf[ct], sa[r]);
      sd[r] = fmaf(accv[ct][r], adf[ct], sd[r]);
    }
#pragma unroll
  for (int off = 1; off <= 8; off <<= 1)
#pragma unroll
    for (int r = 0; r < 4; ++r) {
      sa[r] += __shfl_xor(sa[r], off, 64);
      sd[r] += __shfl_xor(sd[r], off, 64);
    }
  if (nn == 0) {
#pragma unroll
    for (int r = 0; r < 4; ++r) {
      al2[(size_t)(row0 + quad * 4 + r) * 8 + wv] = sa[r];
      al2[(size_t)(row0 + quad * 4 + r) * 8 + 4 + wv] = sd[r];
    }
  }
}

// ------- fused agg3 + node-MLP heads (wcat loaded AFTER agg) -------
__global__ __launch_bounds__(256) void k_aggheads(const __half* __restrict__ h,
                                                  const float* __restrict__ al,
                                                  const int* __restrict__ cnt,
                                                  const int* __restrict__ csr,
                                                  const float* __restrict__ bias,
                                                  const _Float16* __restrict__ wcat,
                                                  const float* __restrict__ aw2,
                                                  const float* __restrict__ ab2,
                                                  const float* __restrict__ rw2,
                                                  const float* __restrict__ rb2,
                                                  const float* __restrict__ cw2,
                                                  const float* __restrict__ cb2,
                                                  float* __restrict__ emb,
                                                  float* __restrict__ anomaly,
                                                  float* __restrict__ risk,
                                                  float* __restrict__ resource) {
  __shared__ _Float16 xt[16 * 72];
  __shared__ float hb[16][101];
  agg16<false, true>(h, al, cnt, csr, bias, emb, xt);
  __syncthreads();
  const int lane = threadIdx.x & 63;
  const int wv = threadIdx.x >> 6;
  const int quad = lane >> 4, nn = lane & 15;
  const int nct = (wv < 2) ? 2 : 1;
  f16x8 af[2];
#pragma unroll
  for (int kc = 0; kc < 2; ++kc)
    af[kc] = *(const f16x8*)(xt + nn * 72 + kc * 32 + quad * 8);
  for (int m = 0; m < nct; ++m) {
    const int ct = (m == 0) ? wv : (4 + wv);
    const int col = ct * 16 + nn;
    f16x8 b0 = *(const f16x8*)&wcat[(size_t)col * 64 + quad * 8];
    f16x8 b1 = *(const f16x8*)&wcat[(size_t)col * 64 + 32 + quad * 8];
    f32x4 acc = {0.f, 0.f, 0.f, 0.f};
    acc = __builtin_amdgcn_mfma_f32_16x16x32_f16(af[0], b0, acc, 0, 0, 0);
    acc = __builtin_amdgcn_mfma_f32_16x16x32_f16(af[1], b1, acc, 0, 0, 0);
#pragma unroll
    for (int r = 0; r < 4; ++r)
      hb[quad * 4 + r][col] = fmaxf(acc[r], 0.f);
  }
  __syncthreads();
  if (wv == 0) {
    const int node = lane >> 2, task = lane & 3;
    const float* hrow = hb[node];
    const int n = blockIdx.x * 16 + node;
    if (task == 0) {
      float s = ab2[0];
#pragma unroll
      for (int k = 0; k < 32; ++k) s = fmaf(hrow[k], aw2[k], s);
      anomaly[n] = 1.f / (1.f + __expf(-s));
    } else if (task == 1) {
      float s = rb2[0];
#pragma unroll
      for (int k = 0; k < 32; ++k) s = fmaf(hrow[32 + k], rw2[k], s);
      risk[n] = 1.f / (1.f + __expf(-s));
    } else if (task == 2) {
      float s0 = cb2[0], s1 = cb2[1], s2 = cb2[2];
#pragma unroll
      for (int k = 0; k < 32; ++k) {
        const float v = hrow[64 + k];
        s0 = fmaf(v, cw2[k * 5 + 0], s0);
        s1 = fmaf(v, cw2[k * 5 + 1], s1);
        s2 = fmaf(v, cw2[k * 5 + 2], s2);
      }
      resource[n * 5 + 0] = s0; resource[n * 5 + 1] = s1; resource[n * 5 + 2] = s2;
    } else {
      float s3 = cb2[3], s4 = cb2[4];
#pragma unroll
      for (int k = 0; k < 32; ++k) {
        const float v = hrow[64 + k];
        s3 = fmaf(v, cw2[k * 5 + 3], s3);
        s4 = fmaf(v, cw2[k * 5 + 4], s4);
      }
      resource[n * 5 + 3] = s3; resource[n * 5 + 4] = s4;
    }
  }
}

// ---------------- pooling + graph MLP (1 block per graph; batch is SORTED) -------
__global__ void k_pool(const float* __restrict__ emb, const int* __restrict__ batch,
                       const float* __restrict__ gw1, const float* __restrict__ gb1,
                       const float* __restrict__ gw2, const float* __restrict__ gb2,
                       float* __restrict__ logits) {
  const int g = blockIdx.x;
  const int tid = threadIdx.x;
  const int c = tid & 63, w = tid >> 6;
  int lo = 0, hi = NN;
  while (lo < hi) { int mid = (lo + hi) >> 1; if (batch[mid] < g) lo = mid + 1; else hi = mid; }
  const int start = lo;
  hi = NN;
  while (lo < hi) { int mid = (lo + hi) >> 1; if (batch[mid] < g + 1) lo = mid + 1; else hi = mid; }
  const int end = lo;
  float s = 0.f;
  for (int n = start + w; n < end; n += 4) s += emb[n * 64 + c];
  __shared__ float sm[4][64];
  __shared__ float prow[64];
  sm[w][c] = s;
  __syncthreads();
  if (tid < 64) {
    float v = sm[0][tid] + sm[1][tid] + sm[2][tid] + sm[3][tid];
    prow[tid] = v * (1.f / fmaxf((float)(end - start), 1.f));
  }
  __syncthreads();
  if (tid < 32) {
    float hG = gb1[tid];
    for (int cc = 0; cc < 64; ++cc) hG = fmaf(prow[cc], gw1[cc * 32 + tid], hG);
    hG = fmaxf(hG, 0.f);
    float p[4];
#pragma unroll
    for (int j = 0; j < 4; ++j) p[j] = hG * gw2[tid * 4 + j];
#pragma unroll
    for (int off = 1; off <= 16; off <<= 1) {
#pragma unroll
      for (int j = 0; j < 4; ++j) p[j] += __shfl_xor(p[j], off, 64);
    }
    if (tid == 0) {
#pragma unroll
      for (int j = 0; j < 4; ++j) logits[g * 4 + j] = p[j] + gb2[j];
    }
  }
}

extern "C" void kernel_launch(void* const* d_in, const int* in_sizes, int n_in,
                              void* d_out, int out_size, void* d_ws, size_t ws_size,
                              hipStream_t stream) {
  const float* x = (const float*)d_in[0];
  const int* ei = (const int*)d_in[1];
  const int* batch = (const int*)d_in[2];
  const float* W1 = (const float*)d_in[3];
  const float* as1 = (const float*)d_in[4];
  const float* ad1 = (const float*)d_in[5];
  const float* b1 = (const float*)d_in[6];
  const float* W2 = (const float*)d_in[7];
  const float* as2 = (const float*)d_in[8];
  const float* ad2 = (const float*)d_in[9];
  const float* b2 = (const float*)d_in[10];
  const float* W3 = (const float*)d_in[11];
  const float* as3 = (const float*)d_in[12];
  const float* ad3 = (const float*)d_in[13];
  const float* b3 = (const float*)d_in[14];
  const float* aw1 = (const float*)d_in[15];
  const float* ab1 = (const float*)d_in[16];
  const float* aw2 = (const float*)d_in[17];
  const float* ab2 = (const float*)d_in[18];
  const float* rw1 = (const float*)d_in[19];
  const float* rb1 = (const float*)d_in[20];
  const float* rw2 = (const float*)d_in[21];
  const float* rb2 = (const float*)d_in[22];
  const float* cw1 = (const float*)d_in[23];
  const float* cb1 = (const float*)d_in[24];
  const float* cw2 = (const float*)d_in[25];
  const float* cb2 = (const float*)d_in[26];
  const float* gw1 = (const float*)d_in[27];
  const float* gb1 = (const float*)d_in[28];
  const float* gw2 = (const float*)d_in[29];
  const float* gb2 = (const float*)d_in[30];

  float* out = (float*)d_out;
  float* emb = out;                       // [N,64]
  float* anomaly = out + NN * 64;         // [N]
  float* risk = anomaly + NN;             // [N]
  float* resource = risk + NN;            // [N,5]
  float* logits = resource + NN * 5;      // [G,4]

  char* ws = (char*)d_ws;
  int* cnt = (int*)ws;            ws += (size_t)NN * 4;   // memset target
  int* csr = (int*)ws;            ws += (size_t)NN * PAD * 4;
  __half* hA = (__half*)ws;       ws += (size_t)NN * 256 * 2;
  float* alA = (float*)ws;        ws += (size_t)NN * 8 * 4;
  __half* hB = (__half*)ws;       ws += (size_t)NN * 256 * 2;
  float* alB = (float*)ws;        ws += (size_t)NN * 8 * 4;
  _Float16* wt1 = (_Float16*)ws;  ws += (size_t)32768 * 2;
  _Float16* wt2 = (_Float16*)ws;  ws += (size_t)16384 * 2;
  _Float16* wt3 = (_Float16*)ws;  ws += (size_t)16384 * 2;
  _Float16* wcat = (_Float16*)ws; ws += (size_t)6144 * 2;

  hipMemsetAsync(cnt, 0, (size_t)NN * 4, stream);
  k_fill<<<NFB + 280, 256, 0, stream>>>(ei, cnt, csr, W1, W2, W3, aw1, rw1, cw1,
                                        wt1, wt2, wt3, wcat);

  // layer 1 linear (fp32 x, in-register cvt)
  k_mm<128, float><<<512, 256, 0, stream>>>(x, wt1, as1, ad1, hA, alA);
  // agg1 + linear2 fused
  k_aggmm<<<NT, 256, 0, stream>>>(hA, alA, cnt, csr, b1, wt2, as2, ad2, hB, alB);
  // agg2 + linear3 fused
  k_aggmm<<<NT, 256, 0, stream>>>(hB, alB, cnt, csr, b2, wt3, as3, ad3, hA, alA);
  // agg3 + node-MLP heads fused
  k_aggheads<<<NT, 256, 0, stream>>>(hA, alA, cnt, csr, b3, wcat, aw2, ab2, rw2, rb2,
                                     cw2, cb2, emb, anomaly, risk, resource);
  k_pool<<<GG, 256, 0, stream>>>(emb, batch, gw1, gb1, gw2, gb2, logits);
}